// Round 1
// baseline (18269.872 us; speedup 1.0000x reference)
//
#include <hip/hip_runtime.h>
#include <math.h>

// Problem dims (fixed by setup_inputs)
#define D    1024
#define NH   16
#define NKV  8
#define DK   64
#define FD   2752
#define SEQ  2048
#define BS   2
#define NL   4
#define VOC  32000
#define M_TOT (BS*SEQ)      // 4096 rows
#define KVD  (NKV*DK)       // 512
#define EPS_RMS 1e-6f

// ---------------- embedding lookup ----------------
__global__ __launch_bounds__(256) void embed_kernel(const int* __restrict__ tokens,
    const float* __restrict__ emb, float* __restrict__ x) {
  int row = blockIdx.x;                 // 0..M_TOT-1
  int tok = tokens[row];
  const float4* src = (const float4*)(emb + (size_t)tok * D);
  float4* dst = (float4*)(x + (size_t)row * D);
  dst[threadIdx.x] = src[threadIdx.x];  // 256 threads * float4 = 1024 floats
}

// ---------------- RMSNorm ----------------
__global__ __launch_bounds__(256) void rmsnorm_kernel(const float* __restrict__ x,
    const float* __restrict__ g, float* __restrict__ h) {
  int row = blockIdx.x, tid = threadIdx.x;
  const float4* xr = (const float4*)(x + (size_t)row * D);
  float4 v = xr[tid];
  float ss = v.x*v.x + v.y*v.y + v.z*v.z + v.w*v.w;
  __shared__ float red[256];
  red[tid] = ss;
  __syncthreads();
  for (int s = 128; s > 0; s >>= 1) {
    if (tid < s) red[tid] += red[tid + s];
    __syncthreads();
  }
  float inv = 1.0f / sqrtf(red[0] / (float)D + EPS_RMS);
  float4 gv = ((const float4*)g)[tid];
  float4 o;
  o.x = v.x * inv * gv.x;
  o.y = v.y * inv * gv.y;
  o.z = v.z * inv * gv.z;
  o.w = v.w * inv * gv.w;
  ((float4*)(h + (size_t)row * D))[tid] = o;
}

// ---------------- generic fp32 GEMM: C = A(MxK) * W + bias (+Rsd) ----------------
// wT==0: W is (K,N) row-major.  wT==1: W is (N,K) row-major (B-transposed, for logits).
// 64x64 tile, BK=16, 256 threads, 4x4 micro-tile per thread.
// A staged transposed in LDS so inner loop does two ds_read_b128 per k-step.
__global__ __launch_bounds__(256) void gemm_kernel(
    const float* __restrict__ A, const float* __restrict__ W,
    const float* __restrict__ bias, const float* __restrict__ Rsd,
    float* __restrict__ C, int M, int N, int K, int wT) {
  __shared__ float As[16][68];   // [k][m], pad 68 (16B-aligned rows, conflict-free)
  __shared__ float Bs[16][68];   // [k][n]
  int tid = threadIdx.x;
  int tx = tid & 15, ty = tid >> 4;
  int n0 = blockIdx.x * 64, m0 = blockIdx.y * 64;
  float acc[4][4] = {};
  for (int k0 = 0; k0 < K; k0 += 16) {
    {   // A tile: 64 rows x 16 cols, one float4 per thread, store transposed
      int r = tid >> 2, c4 = tid & 3;
      float4 a = *(const float4*)(A + (size_t)(m0 + r) * K + k0 + c4 * 4);
      As[c4*4+0][r] = a.x; As[c4*4+1][r] = a.y;
      As[c4*4+2][r] = a.z; As[c4*4+3][r] = a.w;
    }
    if (!wT) {  // W (K,N): 16 rows x 64 cols
      int kr = tid >> 4, n4 = tid & 15;
      float4 b = *(const float4*)(W + (size_t)(k0 + kr) * N + n0 + n4 * 4);
      *(float4*)&Bs[kr][n4*4] = b;
    } else {    // W (N,K): 64 n-rows x 16 k-cols
      int nr = tid >> 2, c4 = tid & 3;
      float4 w = *(const float4*)(W + (size_t)(n0 + nr) * K + k0 + c4 * 4);
      Bs[c4*4+0][nr] = w.x; Bs[c4*4+1][nr] = w.y;
      Bs[c4*4+2][nr] = w.z; Bs[c4*4+3][nr] = w.w;
    }
    __syncthreads();
#pragma unroll
    for (int kk = 0; kk < 16; ++kk) {
      float4 av = *(const float4*)&As[kk][ty*4];
      float4 bv = *(const float4*)&Bs[kk][tx*4];
      float a[4] = {av.x, av.y, av.z, av.w};
      float b[4] = {bv.x, bv.y, bv.z, bv.w};
#pragma unroll
      for (int i = 0; i < 4; ++i)
#pragma unroll
        for (int j = 0; j < 4; ++j)
          acc[i][j] += a[i] * b[j];
    }
    __syncthreads();
  }
#pragma unroll
  for (int i = 0; i < 4; ++i) {
    int row = m0 + ty*4 + i;
    int col = n0 + tx*4;
    float4 o = {acc[i][0], acc[i][1], acc[i][2], acc[i][3]};
    if (bias) {
      o.x += bias[col];   o.y += bias[col+1];
      o.z += bias[col+2]; o.w += bias[col+3];
    }
    if (Rsd) {
      float4 r = *(const float4*)(Rsd + (size_t)row * N + col);
      o.x += r.x; o.y += r.y; o.z += r.z; o.w += r.w;
    }
    *(float4*)(C + (size_t)row * N + col) = o;
  }
}

// ---------------- RoPE + transpose (B,S,nh,dk) -> (B,nh,S,dk) ----------------
__global__ __launch_bounds__(256) void rope_kernel(const float* __restrict__ in,
    float* __restrict__ out, const float* __restrict__ fc, const float* __restrict__ fs,
    int nh) {
  int idx = blockIdx.x * 256 + threadIdx.x;   // BS*SEQ*nh*32 threads, one pair each
  int i  = idx & 31;
  int hh = (idx >> 5) % nh;
  int s  = (idx / (32 * nh)) % SEQ;
  int b  = idx / (32 * nh * SEQ);
  const float* ip = in + (((size_t)(b * SEQ + s) * nh + hh) * DK);
  float xr = ip[2*i], xi = ip[2*i+1];
  float c = fc[s*32 + i], sn = fs[s*32 + i];
  float* op = out + (((size_t)(b * nh + hh) * SEQ + s) * DK);
  op[2*i]   = xr * c - xi * sn;
  op[2*i+1] = xr * sn + xi * c;
}

// ---------------- V transpose (B,S,NKV,DK) -> (B,NKV,S,DK) ----------------
__global__ __launch_bounds__(256) void transpose_v_kernel(const float* __restrict__ in,
    float* __restrict__ out) {
  int idx = blockIdx.x * 256 + threadIdx.x;   // BS*SEQ*NKV*DK
  int d  = idx & 63;
  int hh = (idx >> 6) % NKV;
  int s  = (idx / (64 * NKV)) % SEQ;
  int b  = idx / (64 * NKV * SEQ);
  out[((size_t)(b * NKV + hh) * SEQ + s) * DK + d] = in[idx];
}

// ---------------- flash attention: one wave per (b,h,query) ----------------
__global__ __launch_bounds__(64) void attn_kernel(const float* __restrict__ qT,
    const float* __restrict__ kT, const float* __restrict__ vT,
    float* __restrict__ o) {
  int lane = threadIdx.x;
  int qi = blockIdx.x, hh = blockIdx.y, b = blockIdx.z;
  int kvh = hh / (NH / NKV);
  const float* qrow  = qT + ((size_t)(b * NH  + hh ) * SEQ + qi) * DK;
  const float* kbase = kT + ((size_t)(b * NKV + kvh) * SEQ) * DK;
  const float* vbase = vT + ((size_t)(b * NKV + kvh) * SEQ) * DK;
  __shared__ float qs[DK];
  __shared__ float ks[64 * 65];
  __shared__ float ps[64];
  qs[lane] = qrow[lane];
  float m = -1e30f, l = 0.f, acc = 0.f;
  int ntile = qi / 64 + 1;
  for (int t = 0; t < ntile; ++t) {
    int t0 = t * 64;
    __syncthreads();   // protect ks/ps from prev iter, publish qs on t=0
#pragma unroll 8
    for (int j = 0; j < 64; ++j)
      ks[j * 65 + lane] = kbase[(size_t)(t0 + j) * DK + lane];
    __syncthreads();
    float s = 0.f;
#pragma unroll
    for (int d = 0; d < 64; ++d)
      s += qs[d] * ks[lane * 65 + d];
    s *= 0.125f;                      // 1/sqrt(64)
    if (t0 + lane > qi) s = -1e30f;   // causal mask
    float mt = s;
    for (int off = 32; off > 0; off >>= 1) mt = fmaxf(mt, __shfl_xor(mt, off, 64));
    float mn = fmaxf(m, mt);
    float p  = __expf(s - mn);
    float ls = p;
    for (int off = 32; off > 0; off >>= 1) ls += __shfl_xor(ls, off, 64);
    float alpha = __expf(m - mn);
    l = l * alpha + ls;
    m = mn;
    acc *= alpha;
    ps[lane] = p;
    __syncthreads();
    int jmax = min(64, qi - t0 + 1);
    for (int j = 0; j < jmax; ++j)
      acc += ps[j] * vbase[(size_t)(t0 + j) * DK + lane];  // coalesced
  }
  o[((size_t)(b * SEQ + qi)) * D + hh * DK + lane] = acc / l;
}

// ---------------- silu(f1) * f2 -> f1 ----------------
__global__ __launch_bounds__(256) void silu_mul_kernel(float* __restrict__ f1,
    const float* __restrict__ f2) {
  int idx = blockIdx.x * 256 + threadIdx.x;
  float4 a = ((const float4*)f1)[idx];
  float4 b = ((const float4*)f2)[idx];
  a.x = a.x / (1.f + __expf(-a.x)) * b.x;
  a.y = a.y / (1.f + __expf(-a.y)) * b.y;
  a.z = a.z / (1.f + __expf(-a.z)) * b.z;
  a.w = a.w / (1.f + __expf(-a.w)) * b.w;
  ((float4*)f1)[idx] = a;
}

extern "C" void kernel_launch(void* const* d_in, const int* in_sizes, int n_in,
                              void* d_out, int out_size, void* d_ws, size_t ws_size,
                              hipStream_t stream) {
  const int*   tokens = (const int*)  d_in[0];
  const float* emb    = (const float*)d_in[1];
  const float* wq = (const float*)d_in[2];
  const float* bq = (const float*)d_in[3];
  const float* wk = (const float*)d_in[4];
  const float* bk = (const float*)d_in[5];
  const float* wv = (const float*)d_in[6];
  const float* bv = (const float*)d_in[7];
  const float* wo = (const float*)d_in[8];
  const float* bo = (const float*)d_in[9];
  const float* w1 = (const float*)d_in[10];
  const float* b1 = (const float*)d_in[11];
  const float* w2 = (const float*)d_in[12];
  const float* b2 = (const float*)d_in[13];
  const float* w3 = (const float*)d_in[14];
  const float* b3 = (const float*)d_in[15];
  const float* g1 = (const float*)d_in[16];
  const float* g2 = (const float*)d_in[17];
  const float* gpost = (const float*)d_in[18];
  const float* fcos  = (const float*)d_in[19];
  const float* fsin  = (const float*)d_in[20];
  float* out = (float*)d_out;
  float* ws  = (float*)d_ws;

  // Workspace layout (floats). Total needed ~30.94M floats = ~124 MB.
  float* x    = ws;                   // 4,194,304  (B,S,D) residual stream
  float* h    = ws + 4194304;         // 4,194,304  rmsnorm out
  float* qlin = ws + 8388608;         // 4,194,304
  float* klin = ws + 12582912;        // 2,097,152
  float* vlin = ws + 14680064;        // 2,097,152
  float* qT   = ws + 16777216;        // 4,194,304  (B,NH,S,DK)
  float* kT   = ws + 20971520;        // 2,097,152  (B,NKV,S,DK)
  float* vT   = ws + 23068672;        // 2,097,152
  float* obuf = qlin;                 // reuse: attention output (B,S,D)
  // FFN temporaries overlap the (dead-by-then) qlin..vT region:
  float* f1   = ws + 8388608;         // 11,272,192 (B,S,FD)
  float* f2   = ws + 19660800;        // 11,272,192 ; end = 30,932,992 floats

  embed_kernel<<<M_TOT, 256, 0, stream>>>(tokens, emb, x);

  for (int l = 0; l < NL; ++l) {
    rmsnorm_kernel<<<M_TOT, 256, 0, stream>>>(x, g1 + (size_t)l*D, h);

    gemm_kernel<<<dim3(D/64,   M_TOT/64), 256, 0, stream>>>(h, wq + (size_t)l*D*D,   bq + (size_t)l*D,   nullptr, qlin, M_TOT, D,   D, 0);
    gemm_kernel<<<dim3(KVD/64, M_TOT/64), 256, 0, stream>>>(h, wk + (size_t)l*D*KVD, bk + (size_t)l*KVD, nullptr, klin, M_TOT, KVD, D, 0);
    gemm_kernel<<<dim3(KVD/64, M_TOT/64), 256, 0, stream>>>(h, wv + (size_t)l*D*KVD, bv + (size_t)l*KVD, nullptr, vlin, M_TOT, KVD, D, 0);

    rope_kernel<<<(BS*SEQ*NH *32)/256, 256, 0, stream>>>(qlin, qT, fcos, fsin, NH);
    rope_kernel<<<(BS*SEQ*NKV*32)/256, 256, 0, stream>>>(klin, kT, fcos, fsin, NKV);
    transpose_v_kernel<<<(BS*SEQ*NKV*DK)/256, 256, 0, stream>>>(vlin, vT);

    attn_kernel<<<dim3(SEQ, NH, BS), 64, 0, stream>>>(qT, kT, vT, obuf);

    // x = x + obuf @ Wo + bo   (residual fused into GEMM epilogue)
    gemm_kernel<<<dim3(D/64, M_TOT/64), 256, 0, stream>>>(obuf, wo + (size_t)l*D*D, bo + (size_t)l*D, x, x, M_TOT, D, D, 0);

    rmsnorm_kernel<<<M_TOT, 256, 0, stream>>>(x, g2 + (size_t)l*D, h);

    gemm_kernel<<<dim3(FD/64, M_TOT/64), 256, 0, stream>>>(h, w1 + (size_t)l*D*FD, b1 + (size_t)l*FD, nullptr, f1, M_TOT, FD, D, 0);
    gemm_kernel<<<dim3(FD/64, M_TOT/64), 256, 0, stream>>>(h, w2 + (size_t)l*D*FD, b2 + (size_t)l*FD, nullptr, f2, M_TOT, FD, D, 0);
    silu_mul_kernel<<<(M_TOT*FD/4)/256, 256, 0, stream>>>(f1, f2);
    // x = x + f1 @ W3 + b3
    gemm_kernel<<<dim3(D/64, M_TOT/64), 256, 0, stream>>>(f1, w3 + (size_t)l*FD*D, b3 + (size_t)l*D, x, x, M_TOT, D, FD, 0);
  }

  rmsnorm_kernel<<<M_TOT, 256, 0, stream>>>(x, gpost, h);
  // logits = h @ embed^T  (NT gemm, no bias)
  gemm_kernel<<<dim3(VOC/64, M_TOT/64), 256, 0, stream>>>(h, emb, nullptr, nullptr, out, M_TOT, VOC, D, 1);
}